// Round 17
// baseline (23211.909 us; speedup 1.0000x reference)
//
#include <hip/hip_runtime.h>

// ---------------------------------------------------------------------------
// Persistent seq2seq LSTM, v17 = v16 + guaranteed 2-block/CU residency:
// __launch_bounds__(512, 4) caps VGPR at 128 so both blocks fit per CU
// (v16's all-zero output = sDead bail = deadlock from 256 non-resident
// blocks). Spin caps 2^22. Otherwise identical to v16:
// 512 blocks x 512 threads; block p owns 8 gate cols (units p*2..p*2+1 x 4
// gates), full K=1536 -> gates complete in-block, c in regs; 16x16 MFMA with
// B cols duplicated (col=l&7), outputs 8..15 discarded; fc on p>=256 (2 cols,
// full K -> final values); softmax on p<128; v12 sync web (UC flags, per-XCD
// leader L2-inv, L1-inv others, fence-free y/f chains).
// ---------------------------------------------------------------------------

#define TS 384

typedef __attribute__((ext_vector_type(8))) short bf16x8;
typedef __attribute__((ext_vector_type(4))) float f32x4;

#define WS_XR 8192u
#define XR_SLOT 262144u
#define WS_HP (WS_XR + 4u*XR_SLOT)
#define HP_BUF 524288u
#define WS_FPN (WS_HP + 2u*HP_BUF)
#define WS_TOTAL (WS_FPN + 262144u)

#define MFMA __builtin_amdgcn_mfma_f32_16x16x32_bf16
#define SPINCAP (1u << 22)

__device__ __forceinline__ unsigned short bf16r(float v) {
  unsigned u = __float_as_uint(v);
  u += 0x7FFFu + ((u >> 16) & 1u);
  return (unsigned short)(u >> 16);
}
__device__ __forceinline__ float bf2f(unsigned short h) {
  return __uint_as_float(((unsigned)h) << 16);
}
__device__ __forceinline__ void split2(float v, short& hi, short& lo) {
  unsigned short h = bf16r(v);
  float r = v - bf2f(h);
  hi = (short)h; lo = (short)bf16r(r);
}
__device__ __forceinline__ float sigm(float v)  { return 1.0f / (1.0f + __expf(-v)); }
__device__ __forceinline__ float tanhfa(float v){ return 1.0f - 2.0f / (__expf(2.0f*v) + 1.0f); }

__device__ __forceinline__ void st_u64(void* p, unsigned long long v) {
  __hip_atomic_store((unsigned long long*)p, v, __ATOMIC_RELAXED, __HIP_MEMORY_SCOPE_AGENT);
}
__device__ __forceinline__ unsigned long long ld_u64(const void* p) {
  return __hip_atomic_load((const unsigned long long*)p, __ATOMIC_RELAXED, __HIP_MEMORY_SCOPE_AGENT);
}
__device__ __forceinline__ void st_u32(unsigned* p, unsigned v) {
  __hip_atomic_store(p, v, __ATOMIC_RELAXED, __HIP_MEMORY_SCOPE_AGENT);
}
__device__ __forceinline__ unsigned ld_u32(const unsigned* p) {
  return __hip_atomic_load(p, __ATOMIC_RELAXED, __HIP_MEMORY_SCOPE_AGENT);
}
__device__ __forceinline__ void st_f32(float* p, float v) {
  __hip_atomic_store(p, v, __ATOMIC_RELAXED, __HIP_MEMORY_SCOPE_AGENT);
}
__device__ __forceinline__ float ld_f32(const float* p) {
  return __hip_atomic_load(p, __ATOMIC_RELAXED, __HIP_MEMORY_SCOPE_AGENT);
}

// ---- sync -------------------------------------------------------------------
__device__ __forceinline__ void setflag(unsigned* flag, unsigned val) {
  asm volatile("s_waitcnt vmcnt(0)" ::: "memory");
  __syncthreads();
  if (threadIdx.x == 0)
    __hip_atomic_store(flag, val, __ATOMIC_RELAXED, __HIP_MEMORY_SCOPE_AGENT);
}
__device__ __forceinline__ void hwait(const unsigned* flags, unsigned* invd,
                                      bool leader, unsigned target, int* sDead) {
  const int t = threadIdx.x;
  if (leader) {
    if (t < 64) {
      const unsigned long long* q = (const unsigned long long*)(flags + t * 8);
      unsigned spins = 0;
      for (;;) {
        unsigned long long q0 = ld_u64(q),     q1 = ld_u64(q + 1);
        unsigned long long q2 = ld_u64(q + 2), q3 = ld_u64(q + 3);
        bool ok = ((unsigned)q0 >= target) && ((unsigned)(q0 >> 32) >= target)
               && ((unsigned)q1 >= target) && ((unsigned)(q1 >> 32) >= target)
               && ((unsigned)q2 >= target) && ((unsigned)(q2 >> 32) >= target)
               && ((unsigned)q3 >= target) && ((unsigned)(q3 >> 32) >= target);
        if (__all(ok)) break;
        if (++spins > SPINCAP) { if (t == 0) *sDead = 1; break; }
      }
    }
    if (t == 0) {
      __builtin_amdgcn_fence(__ATOMIC_ACQUIRE, "agent");
      st_u32(invd, target);
      asm volatile("s_waitcnt vmcnt(0)" ::: "memory");
    }
  } else {
    if (t == 0) {
      unsigned spins = 0;
      while (ld_u32(invd) < target) {
        if (++spins > SPINCAP) { *sDead = 1; break; }
      }
      asm volatile("buffer_inv sc0" ::: "memory");
      asm volatile("s_waitcnt vmcnt(0)" ::: "memory");
    }
  }
  __syncthreads();
}
template<int NF>
__device__ __forceinline__ void waitN(const unsigned* flags, unsigned target, int* sDead) {
  const int t = threadIdx.x;
  if (t < 64) {
    constexpr int PU = NF / 128;
    const unsigned long long* q = (const unsigned long long*)(flags + t * (PU * 2));
    unsigned spins = 0;
    for (;;) {
      bool ok = true;
      #pragma unroll
      for (int i = 0; i < PU; ++i) {
        unsigned long long v = ld_u64(q + i);
        if (!(((unsigned)v >= target) && ((unsigned)(v >> 32) >= target))) ok = false;
      }
      if (__all(ok)) break;
      if (++spins > SPINCAP) { if (t == 0) *sDead = 1; break; }
    }
  }
  __syncthreads();
}

// ---- weight loaders --------------------------------------------------------
__device__ void load_gw(const float* __restrict__ Wx, const float* __restrict__ Wh,
                        int p, short* sBh, short* sBl) {
  for (int idx = threadIdx.x; idx < 12288; idx += 512) {
    int kb = idx >> 8, rem = idx & 255;
    int c8 = rem >> 5, kk = rem & 31;
    int k = kb * 32 + kk;
    int gcol = (c8 >> 1) * 1024 + p * 2 + (c8 & 1);
    float wv = (k < 512) ? Wx[(size_t)k * 4096 + gcol]
                         : Wh[(size_t)(k - 512) * 4096 + gcol];
    short hi, lo; split2(wv, hi, lo);
    sBh[idx] = hi; sBl[idx] = lo;
  }
}
__device__ void load_fcw(const float* __restrict__ fcW, int f, short* sFh, short* sFl) {
  for (int idx = threadIdx.x; idx < 2048; idx += 512) {
    int kb = idx >> 6, rem = idx & 63;
    int c = rem >> 5, kk = rem & 31;
    int unit = kb * 32 + kk;
    int col = f * 2 + c;
    short hi, lo; split2(fcW[(size_t)unit * 512 + col], hi, lo);
    sFh[idx] = hi; sFl[idx] = lo;
  }
}

// ---- gate GEMM -------------------------------------------------------------
template<int NKB, int D>
__device__ __forceinline__ void gg(const short* AH_, const short* AL_,
    const short* BH_, const short* BL_, int mt, int l,
    int kbA0, int kbB0, f32x4* acc)
{
  const bf16x8* AH = (const bf16x8*)AH_;
  const bf16x8* AL = (const bf16x8*)AL_;
  const int boff = ((l & 7) * 32) + ((l >> 4) << 3);
  bf16x8 pah[D], pal[D];
  #pragma unroll
  for (int i = 0; i < D; ++i) {
    pah[i] = AH[((kbA0 + i) * 8 + mt) * 64 + l];
    pal[i] = AL[((kbA0 + i) * 8 + mt) * 64 + l];
  }
  #pragma unroll
  for (int i = 0; i < NKB; ++i) {
    bf16x8 ah = pah[i % D], al = pal[i % D];
    if (i + D < NKB) {
      pah[i % D] = AH[((kbA0 + i + D) * 8 + mt) * 64 + l];
      pal[i % D] = AL[((kbA0 + i + D) * 8 + mt) * 64 + l];
    }
    bf16x8 bh = *(const bf16x8*)&BH_[(kbB0 + i) * 256 + boff];
    bf16x8 bl = *(const bf16x8*)&BL_[(kbB0 + i) * 256 + boff];
    const int a = (i & 1) * 3;
    acc[a + 0] = MFMA(ah, bh, acc[a + 0], 0, 0, 0);
    acc[a + 1] = MFMA(ah, bl, acc[a + 1], 0, 0, 0);
    acc[a + 2] = MFMA(al, bh, acc[a + 2], 0, 0, 0);
  }
}
__device__ __forceinline__ void gg_finish(f32x4* acc, int mt, int l, float* LDSgate) {
  f32x4 s = (acc[0] + acc[3]) + ((acc[1] + acc[4]) + (acc[2] + acc[5]));
  const int col8 = l & 15;
  if (col8 < 8) {
    const int r0 = mt * 16 + ((l >> 4) << 2);
    #pragma unroll
    for (int j = 0; j < 4; ++j) LDSgate[(r0 + j) * 9 + col8] = s[j];
  }
}

// ---- x conversion ----------------------------------------------------------
__device__ __forceinline__ void conv_x(const float* __restrict__ xsrc,
                                       short* dstH, short* dstL, int p, int tl) {
  if (tl >= 0 && tl < 16) {
    int g = p * 16 + tl;
    int l = g & 63, mt = (g >> 6) & 7, kb = g >> 9;
    int row = mt * 16 + (l & 15), k = kb * 32 + ((l >> 4) << 3);
    const float* xs = xsrc + (size_t)row * 512 + k;
    unsigned long long h64[2] = {0, 0}, l64[2] = {0, 0};
    #pragma unroll
    for (int j = 0; j < 8; ++j) {
      short hi, lo; split2(xs[j], hi, lo);
      h64[j >> 2] |= (unsigned long long)(unsigned short)hi << ((j & 3) * 16);
      l64[j >> 2] |= (unsigned long long)(unsigned short)lo << ((j & 3) * 16);
    }
    int off = g * 8;
    st_u64(dstH + off, h64[0]); st_u64(dstH + off + 4, h64[1]);
    st_u64(dstL + off, l64[0]); st_u64(dstL + off + 4, l64[1]);
  }
}

__global__ void __launch_bounds__(512, 4)
lstm17(const float* __restrict__ x, const float* __restrict__ h0p,
       const float* __restrict__ c0p, const float* __restrict__ eWx,
       const float* __restrict__ eWh, const float* __restrict__ eb,
       const float* __restrict__ dWx, const float* __restrict__ dWh,
       const float* __restrict__ db, const float* __restrict__ fcW,
       const float* __restrict__ fcb, float* __restrict__ out,
       char* __restrict__ ws)
{
  __shared__ __align__(16) short sBh[12288], sBl[12288];
  __shared__ __align__(16) short sFh[2048], sFl[2048];
  __shared__ float LDSgate[128 * 9];
  __shared__ unsigned hsplit[256];
  __shared__ float ybuf[512];
  __shared__ float red[16];
  __shared__ int sDead, sLeader, sXcd;

  const int p = blockIdx.x, t = threadIdx.x;
  const int w = t >> 6, l = t & 63;
  const int mt = w;
  if (t == 0) sDead = 0;

  unsigned* hflag = (unsigned*)ws;
  unsigned* yflag = (unsigned*)(ws + 2048);
  unsigned* fflag = (unsigned*)(ws + 2560);
  unsigned* elect = (unsigned*)(ws + 3584);

  if (t == 0) {
    unsigned xcd;
    asm volatile("s_getreg_b32 %0, hwreg(HW_REG_XCC_ID)" : "=s"(xcd));
    xcd &= 7u;
    sXcd = (int)xcd;
    unsigned old = __hip_atomic_fetch_add(&elect[xcd], 1u, __ATOMIC_ACQ_REL,
                                          __HIP_MEMORY_SCOPE_AGENT);
    sLeader = (old == 0u) ? 1 : 0;
  }
  __syncthreads();
  const bool leader = (sLeader != 0);
  unsigned* invd = (unsigned*)(ws + 3648 + sXcd * 64);

  short* xrH[4]; short* xrL[4];
  #pragma unroll
  for (int s4 = 0; s4 < 4; ++s4) {
    xrH[s4] = (short*)(ws + WS_XR + s4 * XR_SLOT);
    xrL[s4] = (short*)(ws + WS_XR + s4 * XR_SLOT + 131072u);
  }
  short* hpH[2]; short* hpL[2];
  #pragma unroll
  for (int b2 = 0; b2 < 2; ++b2) {
    hpH[b2] = (short*)(ws + WS_HP + b2 * HP_BUF);
    hpL[b2] = (short*)(ws + WS_HP + b2 * HP_BUF + 262144u);
  }
  float* fp = (float*)(ws + WS_FPN);

  const int row_pw = t & 127, u_pw = (t >> 7) & 1;

  // ================= init =================
  load_gw(eWx, eWh, p, sBh, sBl);
  conv_x(x, xrH[0], xrL[0], p, t);
  conv_x(x + 65536, xrH[1], xrL[1], p, (t >= 16 && t < 32) ? (t - 16) : -1);
  if (t < 32) {
    int hg = p * 32 + t;
    int ll = hg & 63, mtt = (hg >> 6) & 7, hk = hg >> 9;
    int row = mtt * 16 + (ll & 15), k = hk * 32 + ((ll >> 4) << 3);
    const float* hs = h0p + (size_t)row * 1024 + k;
    unsigned long long h64[2] = {0, 0}, l64[2] = {0, 0};
    #pragma unroll
    for (int j = 0; j < 8; ++j) {
      short hi, lo; split2(hs[j], hi, lo);
      h64[j >> 2] |= (unsigned long long)(unsigned short)hi << ((j & 3) * 16);
      l64[j >> 2] |= (unsigned long long)(unsigned short)lo << ((j & 3) * 16);
    }
    int off = hg * 8;
    st_u64(hpH[0] + off, h64[0]); st_u64(hpH[0] + off + 4, h64[1]);
    st_u64(hpL[0] + off, l64[0]); st_u64(hpL[0] + off + 4, l64[1]);
  }
  float creg = 0.f, bq0 = 0.f, bq1 = 0.f, bq2 = 0.f, bq3 = 0.f;
  if (t < 256) {
    int ug = p * 2 + u_pw;
    creg = c0p[(size_t)row_pw * 1024 + ug];
    bq0 = eb[0 * 1024 + ug]; bq1 = eb[1 * 1024 + ug];
    bq2 = eb[2 * 1024 + ug]; bq3 = eb[3 * 1024 + ug];
  }
  setflag(&hflag[p], 1u);
  hwait(hflag, invd, leader, 1u, &sDead);
  if (sDead) return;

  // ================= encoder =================
  for (int st = 0; st < TS; ++st) {
    int rb = st & 1, wb = rb ^ 1, xs = st & 3;
    f32x4 z = {0.f, 0.f, 0.f, 0.f};
    f32x4 acc[6] = {z, z, z, z, z, z};
    gg<16, 4>(xrH[xs], xrL[xs], sBh, sBl, mt, l, 0, 0, acc);
    hwait(hflag, invd, leader, (unsigned)(st + 1), &sDead);
    if (sDead) return;
    gg<32, 4>(hpH[rb], hpL[rb], sBh, sBl, mt, l, 0, 16, acc);
    gg_finish(acc, mt, l, LDSgate);
    __syncthreads();
    if (t < 256) {
      float g0 = LDSgate[row_pw * 9 + 0 + u_pw] + bq0;
      float g1 = LDSgate[row_pw * 9 + 2 + u_pw] + bq1;
      float g2 = LDSgate[row_pw * 9 + 4 + u_pw] + bq2;
      float g3 = LDSgate[row_pw * 9 + 6 + u_pw] + bq3;
      creg = sigm(g1) * creg + sigm(g0) * tanhfa(g2);
      float h = sigm(g3) * tanhfa(creg);
      short hi, lo; split2(h, hi, lo);
      hsplit[u_pw * 128 + row_pw] = ((unsigned)(unsigned short)hi << 16) | (unsigned short)lo;
    } else if (st + 2 < TS) {
      conv_x(x + (size_t)(st + 2) * 65536, xrH[(st + 2) & 3], xrL[(st + 2) & 3], p, t - 256);
    }
    __syncthreads();
    if (t < 128) {
      int r = t;
      unsigned h0v = hsplit[r], h1v = hsplit[128 + r];
      unsigned hi32 = (h0v >> 16) | ((h1v >> 16) << 16);
      unsigned lo32 = (h0v & 0xFFFFu) | ((h1v & 0xFFFFu) << 16);
      int kb = p >> 4, mtt = r >> 4;
      int lane_ = (((p >> 2) & 3) << 4) | (r & 15);
      int j = (p * 2) & 7;
      int off = ((kb * 8 + mtt) * 64 + lane_) * 8 + j;
      st_u32((unsigned*)(hpH[wb] + off), hi32);
      st_u32((unsigned*)(hpL[wb] + off), lo32);
    }
    setflag(&hflag[p], (unsigned)(st + 2));
  }

  // ================= switch to decoder =================
  load_gw(dWx, dWh, p, sBh, sBl);
  if (p >= 256) load_fcw(fcW, p - 256, sFh, sFl);
  if (t < 16) {
    int off = (p * 16 + t) * 8;
    st_u64(xrH[0] + off, 0ull); st_u64(xrH[0] + off + 4, 0ull);
    st_u64(xrL[0] + off, 0ull); st_u64(xrL[0] + off + 4, 0ull);
  }
  creg = 0.0f;
  if (t < 256) {
    int ug = p * 2 + u_pw;
    bq0 = db[0 * 1024 + ug]; bq1 = db[1 * 1024 + ug];
    bq2 = db[2 * 1024 + ug]; bq3 = db[3 * 1024 + ug];
  }
  float fcb_r = fcb[t];
  setflag(&hflag[p], (unsigned)(TS + 2));

  // ================= decoder =================
  const unsigned DB = (unsigned)(TS + 2);
  for (int st = 0; st < TS; ++st) {
    const int rb = st & 1, wb = rb ^ 1;
    f32x4 z = {0.f, 0.f, 0.f, 0.f};
    f32x4 acc[6] = {z, z, z, z, z, z};
    hwait(hflag, invd, leader, DB + (unsigned)st, &sDead);
    if (sDead) return;
    if (p >= 256) {
      if (st >= 1) {
        const int boff2 = ((l & 1) * 32) + ((l >> 4) << 3);
        const bf16x8* AH = (const bf16x8*)hpH[rb];
        const bf16x8* AL = (const bf16x8*)hpL[rb];
        f32x4 a0 = z, a1 = z, a2 = z, a3 = z, a4 = z, a5 = z;
        #pragma unroll
        for (int kb = 0; kb < 32; ++kb) {
          bf16x8 ah = AH[(kb * 8 + mt) * 64 + l];
          bf16x8 al = AL[(kb * 8 + mt) * 64 + l];
          bf16x8 bh = *(const bf16x8*)&sFh[kb * 64 + boff2];
          bf16x8 bl = *(const bf16x8*)&sFl[kb * 64 + boff2];
          if ((kb & 1) == 0) {
            a0 = MFMA(ah, bh, a0, 0, 0, 0);
            a1 = MFMA(ah, bl, a1, 0, 0, 0);
            a2 = MFMA(al, bh, a2, 0, 0, 0);
          } else {
            a3 = MFMA(ah, bh, a3, 0, 0, 0);
            a4 = MFMA(ah, bl, a4, 0, 0, 0);
            a5 = MFMA(al, bh, a5, 0, 0, 0);
          }
        }
        f32x4 s = (a0 + a3) + ((a1 + a4) + (a2 + a5));
        if ((l & 15) < 2) {
          int col = (p - 256) * 2 + (l & 1);
          int r0 = mt * 16 + ((l >> 4) << 2);
          #pragma unroll
          for (int j = 0; j < 4; ++j)
            st_f32(&fp[(size_t)(r0 + j) * 512 + col], s[j]);
        }
        setflag(&fflag[p - 256], (unsigned)st);
      }
      gg<32, 4>(hpH[rb], hpL[rb], sBh, sBl, mt, l, 0, 16, acc);
      if (st >= 1) { waitN<128>(yflag, (unsigned)st, &sDead); if (sDead) return; }
      gg<16, 4>(xrH[rb], xrL[rb], sBh, sBl, mt, l, 0, 0, acc);
    } else {
      gg<32, 4>(hpH[rb], hpL[rb], sBh, sBl, mt, l, 0, 16, acc);
      if (p < 128 && st >= 1) {
        waitN<256>(fflag, (unsigned)st, &sDead);
        if (sDead) return;
        float v = fcb_r + ld_f32(&fp[(size_t)p * 512 + t]);
        float mx = v;
        #pragma unroll
        for (int o = 32; o > 0; o >>= 1) mx = fmaxf(mx, __shfl_xor(mx, o));
        if (l == 0) red[w] = mx;
        __syncthreads();
        mx = red[0];
        #pragma unroll
        for (int i = 1; i < 8; ++i) mx = fmaxf(mx, red[i]);
        float e = __expf(v - mx);
        float ss = e;
        #pragma unroll
        for (int o = 32; o > 0; o >>= 1) ss += __shfl_xor(ss, o);
        if (l == 0) red[8 + w] = ss;
        __syncthreads();
        ss = (red[8] + red[9]) + (red[10] + red[11])
           + (red[12] + red[13]) + (red[14] + red[15]);
        float y = e / ss;
        st_f32(&out[((size_t)(st - 1) * 128 + p) * 512 + t], y);
        ybuf[t] = y;
        __syncthreads();
        if (t < 64) {
          int kb = t >> 2, seg = t & 3;
          int k = kb * 32 + seg * 8;
          int lane_ = (seg << 4) | (p & 15), mtt = p >> 4;
          int off = ((kb * 8 + mtt) * 64 + lane_) * 8;
          unsigned long long h64[2] = {0, 0}, l64[2] = {0, 0};
          #pragma unroll
          for (int j = 0; j < 8; ++j) {
            short hi, lo; split2(ybuf[k + j], hi, lo);
            h64[j >> 2] |= (unsigned long long)(unsigned short)hi << ((j & 3) * 16);
            l64[j >> 2] |= (unsigned long long)(unsigned short)lo << ((j & 3) * 16);
          }
          st_u64(xrH[rb] + off, h64[0]); st_u64(xrH[rb] + off + 4, h64[1]);
          st_u64(xrL[rb] + off, l64[0]); st_u64(xrL[rb] + off + 4, l64[1]);
        }
        setflag(&yflag[p], (unsigned)st);
      }
      if (st >= 1) { waitN<128>(yflag, (unsigned)st, &sDead); if (sDead) return; }
      gg<16, 4>(xrH[rb], xrL[rb], sBh, sBl, mt, l, 0, 0, acc);
    }
    gg_finish(acc, mt, l, LDSgate);
    __syncthreads();
    if (t < 256) {
      float g0 = LDSgate[row_pw * 9 + 0 + u_pw] + bq0;
      float g1 = LDSgate[row_pw * 9 + 2 + u_pw] + bq1;
      float g2 = LDSgate[row_pw * 9 + 4 + u_pw] + bq2;
      float g3 = LDSgate[row_pw * 9 + 6 + u_pw] + bq3;
      creg = sigm(g1) * creg + sigm(g0) * tanhfa(g2);
      float h = sigm(g3) * tanhfa(creg);
      short hi, lo; split2(h, hi, lo);
      hsplit[u_pw * 128 + row_pw] = ((unsigned)(unsigned short)hi << 16) | (unsigned short)lo;
    }
    __syncthreads();
    if (t < 128) {
      int r = t;
      unsigned h0v = hsplit[r], h1v = hsplit[128 + r];
      unsigned hi32 = (h0v >> 16) | ((h1v >> 16) << 16);
      unsigned lo32 = (h0v & 0xFFFFu) | ((h1v & 0xFFFFu) << 16);
      int kb = p >> 4, mtt = r >> 4;
      int lane_ = (((p >> 2) & 3) << 4) | (r & 15);
      int j = (p * 2) & 7;
      int off = ((kb * 8 + mtt) * 64 + lane_) * 8 + j;
      st_u32((unsigned*)(hpH[wb] + off), hi32);
      st_u32((unsigned*)(hpL[wb] + off), lo32);
    }
    setflag(&hflag[p], DB + (unsigned)(st + 1));
  }

  // ================= epilogue: fc+softmax for step TS-1 =================
  {
    const int rb = TS & 1;
    hwait(hflag, invd, leader, DB + (unsigned)TS, &sDead);
    if (sDead) return;
    if (p >= 256) {
      const int boff2 = ((l & 1) * 32) + ((l >> 4) << 3);
      const bf16x8* AH = (const bf16x8*)hpH[rb];
      const bf16x8* AL = (const bf16x8*)hpL[rb];
      f32x4 z = {0.f, 0.f, 0.f, 0.f};
      f32x4 a0 = z, a1 = z, a2 = z, a3 = z, a4 = z, a5 = z;
      #pragma unroll
      for (int kb = 0; kb < 32; ++kb) {
        bf16x8 ah = AH[(kb * 8 + mt) * 64 + l];
        bf16x8 al = AL[(kb * 8 + mt) * 64 + l];
        bf16x8 bh = *(const bf16x8*)&sFh[kb * 64 + boff2];
        bf16x8 bl = *(const bf16x8*)&sFl[kb * 64 + boff2];
        if ((kb & 1) == 0) {
          a0 = MFMA(ah, bh, a0, 0, 0, 0);
          a1 = MFMA(ah, bl, a1, 0, 0, 0);
          a2 = MFMA(al, bh, a2, 0, 0, 0);
        } else {
          a3 = MFMA(ah, bh, a3, 0, 0, 0);
          a4 = MFMA(ah, bl, a4, 0, 0, 0);
          a5 = MFMA(al, bh, a5, 0, 0, 0);
        }
      }
      f32x4 s = (a0 + a3) + ((a1 + a4) + (a2 + a5));
      if ((l & 15) < 2) {
        int col = (p - 256) * 2 + (l & 1);
        int r0 = mt * 16 + ((l >> 4) << 2);
        #pragma unroll
        for (int j = 0; j < 4; ++j)
          st_f32(&fp[(size_t)(r0 + j) * 512 + col], s[j]);
      }
      setflag(&fflag[p - 256], (unsigned)TS);
    } else if (p < 128) {
      waitN<256>(fflag, (unsigned)TS, &sDead);
      if (sDead) return;
      float v = fcb_r + ld_f32(&fp[(size_t)p * 512 + t]);
      float mx = v;
      #pragma unroll
      for (int o = 32; o > 0; o >>= 1) mx = fmaxf(mx, __shfl_xor(mx, o));
      if (l == 0) red[w] = mx;
      __syncthreads();
      mx = red[0];
      #pragma unroll
      for (int i = 1; i < 8; ++i) mx = fmaxf(mx, red[i]);
      float e = __expf(v - mx);
      float ss = e;
      #pragma unroll
      for (int o = 32; o > 0; o >>= 1) ss += __shfl_xor(ss, o);
      if (l == 0) red[8 + w] = ss;
      __syncthreads();
      ss = (red[8] + red[9]) + (red[10] + red[11])
         + (red[12] + red[13]) + (red[14] + red[15]);
      st_f32(&out[((size_t)(TS - 1) * 128 + p) * 512 + t], e / ss);
    }
  }
}

extern "C" void kernel_launch(void* const* d_in, const int* in_sizes, int n_in,
                              void* d_out, int out_size, void* d_ws, size_t ws_size,
                              hipStream_t stream) {
  const float* x   = (const float*)d_in[0];
  const float* h0  = (const float*)d_in[1];
  const float* c0  = (const float*)d_in[2];
  const float* eWx = (const float*)d_in[3];
  const float* eWh = (const float*)d_in[4];
  const float* eb  = (const float*)d_in[5];
  const float* dWx = (const float*)d_in[6];
  const float* dWh = (const float*)d_in[7];
  const float* db  = (const float*)d_in[8];
  const float* fcW = (const float*)d_in[9];
  const float* fcb = (const float*)d_in[10];
  float* out = (float*)d_out;

  if (ws_size < (size_t)WS_TOTAL) {
    (void)hipMemsetAsync(d_out, 0xFF, (size_t)out_size * sizeof(float), stream);
    return;
  }
  (void)hipMemsetAsync(d_ws, 0, 8192, stream);   // flags + elect + invdone
  hipLaunchKernelGGL(lstm17, dim3(512), dim3(512), 0, stream,
                     x, h0, c0, eWx, eWh, eb, dWx, dWh, db, fcW, fcb, out,
                     (char*)d_ws);
}